// Round 10
// baseline (347.741 us; speedup 1.0000x reference)
//
#include <hip/hip_runtime.h>
#include <hip/hip_bf16.h>
#include <math.h>

#define NB 512

typedef __attribute__((ext_vector_type(8))) short short8;
typedef __attribute__((ext_vector_type(4))) float f32x4;
union U4 { uint4 u; short8 s8; };
union BF { __hip_bfloat16 h; ushort us; };

__device__ __forceinline__ int swz(int u) { return u ^ ((u >> 3) & 7); }
__device__ __forceinline__ int idx8(int l, int u) { return l * 8 + (u ^ (l & 7)); }

// ---------------- fused conv trunk, 4 blocks per batch; conv weights converted in-kernel
__global__ __launch_bounds__(256) void conv_trunk(const float* __restrict__ x,
                                                  const float* __restrict__ c1w,
                                                  const float* __restrict__ c1b,
                                                  const float* __restrict__ w2,
                                                  const float* __restrict__ c2b,
                                                  const float* __restrict__ w3,
                                                  const float* __restrict__ c3b,
                                                  const float* __restrict__ in1w,
                                                  const float* __restrict__ in2w,
                                                  const float* __restrict__ ow1,
                                                  const float* __restrict__ ow2,
                                                  __hip_bfloat16* __restrict__ winb,
                                                  __hip_bfloat16* __restrict__ owb,
                                                  __hip_bfloat16* __restrict__ h3b) {
    __shared__ uint4 H1u[1088];
    __shared__ uint4 H2u[1088];
    float* xs = (float*)H2u;
    int t = threadIdx.x, h = blockIdx.x, b = blockIdx.y;
    int lane = t & 63, w = t >> 6, m = lane & 15, quad = lane >> 4;
    int p0 = h * 512 - 6;
    int gbase = h * 1024 - 14;

    const float* xb = x + b * 4096;
    for (int i = t; i < 1080; i += 256) {
        int gx = gbase + i;
        xs[i] = (gx >= 0 && gx < 4096) ? xb[gx] : 0.f;
    }
    // one block converts the mamba weights (consumed 2 launches later)
    if (h == 1 && b == 0) {
        for (int i = t; i < 16384; i += 256)
            winb[i] = __float2bfloat16((i < 8192 ? in1w : in2w)[i & 8191]);
        for (int i = t; i < 8192; i += 256)
            owb[i] = __float2bfloat16((i < 4096 ? ow1 : ow2)[i & 4095]);
    }
    // conv2 B-fragments direct from fp32 (same mapping as former prep_w)
    U4 Bf2[3][2];
#pragma unroll
    for (int ct = 0; ct < 2; ++ct)
#pragma unroll
        for (int tp = 0; tp < 3; ++tp) {
            union { uint4 q; __hip_bfloat16 hh[8]; } o;
#pragma unroll
            for (int j = 0; j < 8; ++j) {
                int g = tp * 32 + quad * 8 + j;
                int tl = (g >> 4) & 1, c1 = g & 15;
                int tap = tp * 2 + tl;
                float v = (tap < 5) ? w2[(ct * 16 + m) * 80 + c1 * 5 + tap] : 0.f;
                o.hh[j] = __float2bfloat16(v);
            }
            Bf2[tp][ct].u = o.q;
        }
    float bv2[2];
#pragma unroll
    for (int ct = 0; ct < 2; ++ct) bv2[ct] = c2b[ct * 16 + m];
    float wv[80], bv1[16];
#pragma unroll
    for (int i = 0; i < 80; ++i) wv[i] = c1w[i];
#pragma unroll
    for (int i = 0; i < 16; ++i) bv1[i] = c1b[i];
    __syncthreads();

    for (int r = t; r < 536; r += 256) {
        int p = p0 + r;
        union { uint4 q[2]; __hip_bfloat16 hh[16]; } o;
        if (p >= 0 && p < 2048) {
            const float* s = xs + 2 * r;
            float s0 = s[0], s1 = s[1], s2 = s[2], s3 = s[3], s4 = s[4], s5 = s[5];
#pragma unroll
            for (int c = 0; c < 16; ++c) {
                const float* wr = wv + c * 5;
                float v0 = fmaf(wr[0], s0, fmaf(wr[1], s1, fmaf(wr[2], s2, fmaf(wr[3], s3, fmaf(wr[4], s4, bv1[c])))));
                float v1 = fmaf(wr[0], s1, fmaf(wr[1], s2, fmaf(wr[2], s3, fmaf(wr[3], s4, fmaf(wr[4], s5, bv1[c])))));
                o.hh[c] = __float2bfloat16(fmaxf(fmaxf(v0, v1), 0.f));
            }
        } else {
            o.q[0] = (uint4){0, 0, 0, 0};
            o.q[1] = (uint4){0, 0, 0, 0};
        }
        H1u[swz(2 * r)] = o.q[0];
        H1u[swz(2 * r + 1)] = o.q[1];
    }
    __syncthreads();

    __hip_bfloat16* H2h = (__hip_bfloat16*)H2u;
    for (int g = w; g < 33; g += 4) {
        f32x4 acc[2];
#pragma unroll
        for (int ct = 0; ct < 2; ++ct) acc[ct] = (f32x4){bv2[ct], bv2[ct], bv2[ct], bv2[ct]};
#pragma unroll
        for (int tp = 0; tp < 3; ++tp) {
            int u = 2 * (g * 16 + m + 2 * tp) + quad;
            U4 av; av.u = H1u[swz(u)];
            acc[0] = __builtin_amdgcn_mfma_f32_16x16x32_bf16(av.s8, Bf2[tp][0].s8, acc[0], 0, 0, 0);
            acc[1] = __builtin_amdgcn_mfma_f32_16x16x32_bf16(av.s8, Bf2[tp][1].s8, acc[1], 0, 0, 0);
        }
        int pp = g * 8 + quad * 2;
#pragma unroll
        for (int ct = 0; ct < 2; ++ct) {
            float o0 = fmaxf(fmaxf(acc[ct][0], acc[ct][1]), 0.f);
            float o1 = fmaxf(fmaxf(acc[ct][2], acc[ct][3]), 0.f);
            int ch = ct * 16 + m;
            int u0 = pp * 4 + (ch >> 3);
            H2h[swz(u0) * 8 + (ch & 7)] = __float2bfloat16(o0);
            H2h[swz(u0 + 4) * 8 + (ch & 7)] = __float2bfloat16(o1);
        }
    }
    __syncthreads();
    if (h == 0 && t < 8) H2u[swz((t >> 2) * 4 + (t & 3))] = (uint4){0, 0, 0, 0};
    if (h == 3 && t < 8) H2u[swz((258 + (t >> 2)) * 4 + (t & 3))] = (uint4){0, 0, 0, 0};
    __syncthreads();

    // conv3 B-fragments direct from fp32
    U4 Bf3[5][4];
#pragma unroll
    for (int ct = 0; ct < 4; ++ct)
#pragma unroll
        for (int kk = 0; kk < 5; ++kk) {
            union { uint4 q; __hip_bfloat16 hh[8]; } o;
#pragma unroll
            for (int j = 0; j < 8; ++j) {
                int c1 = quad * 8 + j;
                o.hh[j] = __float2bfloat16(w3[(ct * 16 + m) * 160 + c1 * 5 + kk]);
            }
            Bf3[kk][ct].u = o.q;
        }
    float bv3[4];
#pragma unroll
    for (int ct = 0; ct < 4; ++ct) bv3[ct] = c3b[ct * 16 + m];

#pragma unroll
    for (int ww = 0; ww < 2; ++ww) {
        int wl = w * 2 + ww;
        float sum[4] = {0.f, 0.f, 0.f, 0.f};
#pragma unroll
        for (int half = 0; half < 2; ++half) {
            int gp = wl * 2 + half;
            f32x4 acc[4];
#pragma unroll
            for (int ct = 0; ct < 4; ++ct) acc[ct] = (f32x4){bv3[ct], bv3[ct], bv3[ct], bv3[ct]};
#pragma unroll
            for (int kk = 0; kk < 5; ++kk) {
                int u = 4 * (gp * 16 + m + kk) + quad;
                U4 av; av.u = H2u[swz(u)];
#pragma unroll
                for (int ct = 0; ct < 4; ++ct)
                    acc[ct] = __builtin_amdgcn_mfma_f32_16x16x32_bf16(av.s8, Bf3[kk][ct].s8, acc[ct], 0, 0, 0);
            }
#pragma unroll
            for (int ct = 0; ct < 4; ++ct) {
                sum[ct] += fmaxf(acc[ct][0], 0.f) + fmaxf(acc[ct][1], 0.f)
                         + fmaxf(acc[ct][2], 0.f) + fmaxf(acc[ct][3], 0.f);
            }
        }
#pragma unroll
        for (int ct = 0; ct < 4; ++ct) {
            float s = sum[ct];
            s += __shfl_xor(s, 16, 64);
            s += __shfl_xor(s, 32, 64);
            sum[ct] = s;
        }
        float sv = (quad == 0) ? sum[0] : (quad == 1) ? sum[1] : (quad == 2) ? sum[2] : sum[3];
        int win = h * 8 + wl;
        h3b[b * 2048 + (quad * 16 + m) * 32 + win] = __float2bfloat16(sv * (1.f / 32.f));
    }
}

// ---------------- MFMA GEMM v4: 64x64 tile, BK=128, register-prefetch, no spill
__global__ __launch_bounds__(256, 2) void lin_gemm_mfma(const __hip_bfloat16* __restrict__ A,
                                                        const float* __restrict__ Bw,
                                                        const float* __restrict__ bias,
                                                        float* __restrict__ C) {
    __shared__ uint4 A_s[64 * 16];   // 16 KB: [row][16 units of 8 bf16], XOR-swizzled
    __shared__ uint4 B_s[64 * 16];   // 16 KB
    int t = threadIdx.x;
    int col0 = blockIdx.x * 64;
    int row0 = blockIdx.y * 64;
    int w = t >> 6, lane = t & 63;
    int m = lane & 15, quad = lane >> 4;
    int lh = w >> 1, eh = w & 1;
    int pr = t >> 4, pu = t & 15;    // staging coords: each thread covers rows pr, pr+16, pr+32, pr+48

    f32x4 acc[2][2];
#pragma unroll
    for (int li = 0; li < 2; ++li)
#pragma unroll
        for (int ei = 0; ei < 2; ++ei) acc[li][ei] = (f32x4){0.f, 0.f, 0.f, 0.f};

    uint4 pa[4];
    float4 pb[8];

    // prefetch k-tile 0 (12 independent loads)
#pragma unroll
    for (int p = 0; p < 4; ++p) {
        int r = pr + p * 16;
        pa[p] = *(const uint4*)(A + (row0 + r) * 2048 + pu * 8);
        const float4* s4 = (const float4*)(Bw + (size_t)(col0 + r) * 2048 + pu * 8);
        pb[2 * p] = s4[0];
        pb[2 * p + 1] = s4[1];
    }

    for (int kt = 0; kt < 16; ++kt) {
        // stage prefetched tile (cvt B at LDS-write time)
#pragma unroll
        for (int p = 0; p < 4; ++p) {
            int r = pr + p * 16;
            A_s[r * 16 + (pu ^ (r & 15))] = pa[p];
            float4 f0 = pb[2 * p], f1 = pb[2 * p + 1];
            union { uint4 q; __hip_bfloat16 hh[8]; } o;
            o.hh[0] = __float2bfloat16(f0.x); o.hh[1] = __float2bfloat16(f0.y);
            o.hh[2] = __float2bfloat16(f0.z); o.hh[3] = __float2bfloat16(f0.w);
            o.hh[4] = __float2bfloat16(f1.x); o.hh[5] = __float2bfloat16(f1.y);
            o.hh[6] = __float2bfloat16(f1.z); o.hh[7] = __float2bfloat16(f1.w);
            B_s[r * 16 + (pu ^ (r & 15))] = o.q;
        }
        __syncthreads();
        // prefetch next tile; in flight during the MFMA phase
        if (kt < 15) {
            int k0 = (kt + 1) * 128;
#pragma unroll
            for (int p = 0; p < 4; ++p) {
                int r = pr + p * 16;
                pa[p] = *(const uint4*)(A + (row0 + r) * 2048 + k0 + pu * 8);
                const float4* s4 = (const float4*)(Bw + (size_t)(col0 + r) * 2048 + k0 + pu * 8);
                pb[2 * p] = s4[0];
                pb[2 * p + 1] = s4[1];
            }
        }
#pragma unroll
        for (int c = 0; c < 4; ++c) {
            int ua = c * 4 + quad;
            U4 av[2], bv[2];
#pragma unroll
            for (int li = 0; li < 2; ++li) {
                int ra = (lh * 2 + li) * 16 + m;
                av[li].u = A_s[ra * 16 + (ua ^ (ra & 15))];
            }
#pragma unroll
            for (int ei = 0; ei < 2; ++ei) {
                int rb = (eh * 2 + ei) * 16 + m;
                bv[ei].u = B_s[rb * 16 + (ua ^ (rb & 15))];
            }
#pragma unroll
            for (int li = 0; li < 2; ++li)
#pragma unroll
                for (int ei = 0; ei < 2; ++ei)
                    acc[li][ei] = __builtin_amdgcn_mfma_f32_16x16x32_bf16(av[li].s8, bv[ei].s8, acc[li][ei], 0, 0, 0);
        }
        __syncthreads();
    }
#pragma unroll
    for (int li = 0; li < 2; ++li)
#pragma unroll
        for (int ei = 0; ei < 2; ++ei) {
            int col = col0 + (eh * 2 + ei) * 16 + m;
            float bvv = bias[col];
#pragma unroll
            for (int reg = 0; reg < 4; ++reg) {
                int row = row0 + (lh * 2 + li) * 16 + quad * 4 + reg;
                C[row * 4096 + col] = acc[li][ei][reg] + bvv;
            }
        }
}

// ---------------- fused double {layernorm + mamba}, MFMA in/out-proj
struct MambaP {
    const float *lng, *lnb, *cvw, *cvb, *xpw, *dtw, *dtb, *al, *dp;
};

__global__ __launch_bounds__(256) void mamba2_kernel(const float* __restrict__ lin,
                                                     const __hip_bfloat16* __restrict__ winb,
                                                     const __hip_bfloat16* __restrict__ owb,
                                                     MambaP p1, MambaP p2,
                                                     float* __restrict__ out) {
    __shared__ float X[64][68];
    __shared__ float XI[64][68];
    __shared__ float DTS[64][68];
    __shared__ float W12[64][14];
    __shared__ uint4 XBu[512];
    int b = blockIdx.x, t = threadIdx.x;
    int lane = t & 63, w = t >> 6, m = lane & 15, quad = lane >> 4;
    int l0 = w * 16;

    {
        const float4* lin4 = (const float4*)(lin + b * 4096);
        for (int i = t; i < 1024; i += 256) {
            float4 v = lin4[i];
            *(float4*)(&X[i >> 4][(i & 15) * 4]) = v;
        }
    }
    __syncthreads();

    for (int blk = 0; blk < 2; ++blk) {
        MambaP P = blk ? p2 : p1;

        {
            int l = t >> 2, q = t & 3;
            float4 xv[4];
            const float4* xr = (const float4*)(&X[l][q * 16]);
#pragma unroll
            for (int j = 0; j < 4; ++j) xv[j] = xr[j];
            float s = 0.f;
#pragma unroll
            for (int j = 0; j < 4; ++j) s += (xv[j].x + xv[j].y) + (xv[j].z + xv[j].w);
            s += __shfl_xor(s, 1, 4);
            s += __shfl_xor(s, 2, 4);
            float mm = s * (1.f / 64.f);
            float v = 0.f;
#pragma unroll
            for (int j = 0; j < 4; ++j) {
                float dx;
                dx = xv[j].x - mm; v = fmaf(dx, dx, v);
                dx = xv[j].y - mm; v = fmaf(dx, dx, v);
                dx = xv[j].z - mm; v = fmaf(dx, dx, v);
                dx = xv[j].w - mm; v = fmaf(dx, dx, v);
            }
            v += __shfl_xor(v, 1, 4);
            v += __shfl_xor(v, 2, 4);
            float rstd = rsqrtf(v * (1.f / 64.f) + 1e-5f);
            const float4* g4 = (const float4*)(P.lng + q * 16);
            const float4* bb4 = (const float4*)(P.lnb + q * 16);
            union { uint4 qq[2]; __hip_bfloat16 hh[16]; } o;
#pragma unroll
            for (int j = 0; j < 4; ++j) {
                float4 g = g4[j], bb = bb4[j];
                o.hh[j * 4 + 0] = __float2bfloat16((xv[j].x - mm) * rstd * g.x + bb.x);
                o.hh[j * 4 + 1] = __float2bfloat16((xv[j].y - mm) * rstd * g.y + bb.y);
                o.hh[j * 4 + 2] = __float2bfloat16((xv[j].z - mm) * rstd * g.z + bb.z);
                o.hh[j * 4 + 3] = __float2bfloat16((xv[j].w - mm) * rstd * g.w + bb.w);
            }
            XBu[idx8(l, q * 2)] = o.qq[0];
            XBu[idx8(l, q * 2 + 1)] = o.qq[1];
        }
        __syncthreads();

        {
            const uint4* wp = (const uint4*)winb + blk * 1024;
            U4 Bf[8][2];
#pragma unroll
            for (int nt = 0; nt < 8; ++nt)
#pragma unroll
                for (int c = 0; c < 2; ++c)
                    Bf[nt][c].u = wp[(nt * 16 + m) * 8 + c * 4 + quad];
            f32x4 acc[8];
#pragma unroll
            for (int nt = 0; nt < 8; ++nt) acc[nt] = (f32x4){0.f, 0.f, 0.f, 0.f};
#pragma unroll
            for (int c = 0; c < 2; ++c) {
                U4 av; av.u = XBu[idx8(l0 + m, c * 4 + quad)];
#pragma unroll
                for (int nt = 0; nt < 8; ++nt)
                    acc[nt] = __builtin_amdgcn_mfma_f32_16x16x32_bf16(av.s8, Bf[nt][c].s8, acc[nt], 0, 0, 0);
            }
#pragma unroll
            for (int nt = 0; nt < 4; ++nt)
#pragma unroll
                for (int reg = 0; reg < 4; ++reg)
                    XI[l0 + quad * 4 + reg][nt * 16 + m] = acc[nt][reg];
#pragma unroll
            for (int nt = 4; nt < 8; ++nt)
#pragma unroll
                for (int reg = 0; reg < 4; ++reg)
                    X[l0 + quad * 4 + reg][(nt - 4) * 16 + m] = acc[nt][reg];
        }
        __syncthreads();

        {
            int d = t & 63, lg = t >> 6;
            int lc = lg * 16;
            float cur[16];
            float prev = (lc == 0) ? 0.f : XI[lc - 1][d];
#pragma unroll
            for (int j = 0; j < 16; ++j) cur[j] = XI[lc + j][d];
            __syncthreads();
            float w0 = P.cvw[d * 2], w1 = P.cvw[d * 2 + 1], cb = P.cvb[d];
#pragma unroll
            for (int j = 0; j < 16; ++j) {
                float xp = (j == 0) ? prev : cur[j - 1];
                float v = fmaf(w0, xp, fmaf(w1, cur[j], cb));
                XI[lc + j][d] = v / (1.f + __expf(-v));
            }
        }
        __syncthreads();

        {
            int l = t & 63, jg = t >> 6;
            float4 xrow[16];
            const float4* xr = (const float4*)(&XI[l][0]);
#pragma unroll
            for (int k4 = 0; k4 < 16; ++k4) xrow[k4] = xr[k4];
#pragma unroll
            for (int jj = 0; jj < 3; ++jj) {
                int j = jg * 3 + jj;
                const float4* wr = (const float4*)(P.xpw + j * 64);
                float a0 = 0.f, a1 = 0.f, a2 = 0.f, a3 = 0.f;
#pragma unroll
                for (int k4 = 0; k4 < 16; ++k4) {
                    float4 wvv = wr[k4];
                    a0 = fmaf(xrow[k4].x, wvv.x, a0);
                    a1 = fmaf(xrow[k4].y, wvv.y, a1);
                    a2 = fmaf(xrow[k4].z, wvv.z, a2);
                    a3 = fmaf(xrow[k4].w, wvv.w, a3);
                }
                float accv = (a0 + a1) + (a2 + a3);
                int slot = (j < 4) ? j : ((j < 8) ? (4 + (j - 4) * 2) : (5 + (j - 8) * 2));
                W12[l][slot] = accv;
            }
        }
        __syncthreads();

        {
            int l = t & 63, dg = t >> 6;
            float d0 = W12[l][0], d1 = W12[l][1], d2 = W12[l][2], d3 = W12[l][3];
#pragma unroll 4
            for (int jj = 0; jj < 16; ++jj) {
                int d = dg * 16 + jj;
                const float4 wvv = *(const float4*)(P.dtw + d * 4);
                float xdt = fmaf(wvv.x, d0, fmaf(wvv.y, d1, fmaf(wvv.z, d2, fmaf(wvv.w, d3, P.dtb[d]))));
                DTS[d][l] = fmaxf(xdt, 0.f) + __logf(1.f + __expf(-fabsf(xdt)));
            }
        }
        __syncthreads();

        {
            int d = t >> 2, n = t & 3;
            float Aval = -__expf(P.al[d * 4 + n]);
            float dpv = P.dp[d];
            const float* dtrow = &DTS[d][0];
            ushort* YBh = (ushort*)XBu;
            float h = 0.f;
#pragma unroll 4
            for (int l = 0; l < 64; ++l) {
                float dtv = dtrow[l];
                float dA = __expf(dtv * Aval);
                float uv = XI[l][d];
                float2 bc = *(const float2*)(&W12[l][4 + n * 2]);
                h = fmaf(dA, h, dtv * bc.x * uv);
                float part = h * bc.y;
                part += __shfl_xor(part, 1, 4);
                part += __shfl_xor(part, 2, 4);
                if (n == 0) {
                    float zv = X[l][d];
                    float yv = part + dpv * uv;
                    float gy = yv * (zv / (1.f + __expf(-zv)));
                    BF cv; cv.h = __float2bfloat16(gy);
                    YBh[idx8(l, d >> 3) * 8 + (d & 7)] = cv.us;
                }
            }
        }
        __syncthreads();

        {
            const uint4* wp = (const uint4*)owb + blk * 512;
            U4 Bf[4][2];
#pragma unroll
            for (int nt = 0; nt < 4; ++nt)
#pragma unroll
                for (int c = 0; c < 2; ++c)
                    Bf[nt][c].u = wp[(nt * 16 + m) * 8 + c * 4 + quad];
            f32x4 acc[4];
#pragma unroll
            for (int nt = 0; nt < 4; ++nt) acc[nt] = (f32x4){0.f, 0.f, 0.f, 0.f};
#pragma unroll
            for (int c = 0; c < 2; ++c) {
                U4 av; av.u = XBu[idx8(l0 + m, c * 4 + quad)];
#pragma unroll
                for (int nt = 0; nt < 4; ++nt)
                    acc[nt] = __builtin_amdgcn_mfma_f32_16x16x32_bf16(av.s8, Bf[nt][c].s8, acc[nt], 0, 0, 0);
            }
            if (blk == 0) {
#pragma unroll
                for (int nt = 0; nt < 4; ++nt)
#pragma unroll
                    for (int reg = 0; reg < 4; ++reg)
                        X[l0 + quad * 4 + reg][nt * 16 + m] = acc[nt][reg];
            } else {
                float* ob = out + b * 4096;
#pragma unroll
                for (int nt = 0; nt < 4; ++nt)
#pragma unroll
                    for (int reg = 0; reg < 4; ++reg)
                        ob[(l0 + quad * 4 + reg) * 64 + nt * 16 + m] = acc[nt][reg];
            }
        }
        __syncthreads();
    }
}

extern "C" void kernel_launch(void* const* d_in, const int* in_sizes, int n_in,
                              void* d_out, int out_size, void* d_ws, size_t ws_size,
                              hipStream_t stream) {
    const float* x   = (const float*)d_in[0];
    const float* c1w = (const float*)d_in[1];
    const float* c1b = (const float*)d_in[2];
    const float* c2w = (const float*)d_in[3];
    const float* c2b = (const float*)d_in[4];
    const float* c3w = (const float*)d_in[5];
    const float* c3b = (const float*)d_in[6];
    const float* lw  = (const float*)d_in[7];
    const float* lb  = (const float*)d_in[8];

    MambaP p1, p2;
    p1.lng = (const float*)d_in[9];  p1.lnb = (const float*)d_in[10];
    p1.cvw = (const float*)d_in[12]; p1.cvb = (const float*)d_in[13];
    p1.xpw = (const float*)d_in[14]; p1.dtw = (const float*)d_in[15];
    p1.dtb = (const float*)d_in[16]; p1.al  = (const float*)d_in[17];
    p1.dp  = (const float*)d_in[18];
    p2.lng = (const float*)d_in[20]; p2.lnb = (const float*)d_in[21];
    p2.cvw = (const float*)d_in[23]; p2.cvb = (const float*)d_in[24];
    p2.xpw = (const float*)d_in[25]; p2.dtw = (const float*)d_in[26];
    p2.dtb = (const float*)d_in[27]; p2.al  = (const float*)d_in[28];
    p2.dp  = (const float*)d_in[29];
    const float* in1w = (const float*)d_in[11];
    const float* in2w = (const float*)d_in[22];
    const float* ow1  = (const float*)d_in[19];
    const float* ow2  = (const float*)d_in[30];

    const size_t MB = 1024 * 1024;
    char* base = (char*)d_ws;
    __hip_bfloat16* h3b  = (__hip_bfloat16*)base;                           // 2 MB
    float* lin           = (float*)(base + 4 * MB);                         // 8 MB
    __hip_bfloat16* winb = (__hip_bfloat16*)(base + 16 * MB);               // 32 KB
    __hip_bfloat16* owb  = (__hip_bfloat16*)(base + 16 * MB + 256 * 1024);  // 16 KB
    float* outp = (float*)d_out;

    conv_trunk<<<dim3(4, NB), dim3(256), 0, stream>>>(x, c1w, c1b, c2w, c2b, c3w, c3b,
                                                      in1w, in2w, ow1, ow2, winb, owb, h3b);
    lin_gemm_mfma<<<dim3(64, 8), dim3(256), 0, stream>>>(h3b, lw, lb, lin);
    mamba2_kernel<<<dim3(NB), dim3(256), 0, stream>>>(lin, winb, owb, p1, p2, outp);
}

// Round 11
// 242.918 us; speedup vs baseline: 1.4315x; 1.4315x over previous
//
#include <hip/hip_runtime.h>
#include <hip/hip_bf16.h>
#include <math.h>

#define NB 512

typedef __attribute__((ext_vector_type(8))) short short8;
typedef __attribute__((ext_vector_type(4))) float f32x4;
union U4 { uint4 u; short8 s8; };
union BF { __hip_bfloat16 h; ushort us; };

__device__ __forceinline__ int swz(int u) { return u ^ ((u >> 3) & 7); }
__device__ __forceinline__ int idx8(int l, int u) { return l * 8 + (u ^ (l & 7)); }

// ---------------- small prep: conv weight reorg + mamba weight bf16 (148 blocks)
__global__ __launch_bounds__(256) void prep_w(const float* __restrict__ w2,
                                              __hip_bfloat16* __restrict__ w2b,
                                              const float* __restrict__ w3,
                                              __hip_bfloat16* __restrict__ w3b,
                                              const float* __restrict__ in1w,
                                              const float* __restrict__ in2w,
                                              __hip_bfloat16* __restrict__ winb,
                                              const float* __restrict__ ow1,
                                              const float* __restrict__ ow2,
                                              __hip_bfloat16* __restrict__ owb) {
    int i = blockIdx.x * 256 + threadIdx.x;   // 148*256 = 37888
    if (i < 3072) {
        int c2 = i / 96, rest = i - c2 * 96;
        int tp = rest >> 5, r2 = rest & 31;
        int tl = r2 >> 4, c1 = r2 & 15;
        int tap = tp * 2 + tl;
        float v = (tap < 5) ? w2[c2 * 80 + c1 * 5 + tap] : 0.f;
        w2b[i] = __float2bfloat16(v);
    } else if (i < 13312) {
        int j = i - 3072;
        int c3 = j / 160, rest = j - c3 * 160;
        int kk = rest >> 5, c1 = rest & 31;
        w3b[j] = __float2bfloat16(w3[c3 * 160 + c1 * 5 + kk]);
    } else if (i < 29696) {
        int j = i - 13312;
        winb[j] = __float2bfloat16((j < 8192 ? in1w : in2w)[j & 8191]);
    } else {
        int j = i - 29696;
        owb[j] = __float2bfloat16((j < 4096 ? ow1 : ow2)[j & 4095]);
    }
}

// ---------------- fused conv trunk, 4 blocks per batch (halo recompute), ~35 KB LDS
__global__ __launch_bounds__(256) void conv_trunk(const float* __restrict__ x,
                                                  const float* __restrict__ c1w,
                                                  const float* __restrict__ c1b,
                                                  const __hip_bfloat16* __restrict__ w2b,
                                                  const float* __restrict__ c2b,
                                                  const __hip_bfloat16* __restrict__ w3b,
                                                  const float* __restrict__ c3b,
                                                  __hip_bfloat16* __restrict__ h3b) {
    __shared__ uint4 H1u[1088];
    __shared__ uint4 H2u[1088];
    float* xs = (float*)H2u;
    int t = threadIdx.x, h = blockIdx.x, b = blockIdx.y;
    int lane = t & 63, w = t >> 6, m = lane & 15, quad = lane >> 4;
    int p0 = h * 512 - 6;
    int gbase = h * 1024 - 14;

    const float* xb = x + b * 4096;
    for (int i = t; i < 1080; i += 256) {
        int gx = gbase + i;
        xs[i] = (gx >= 0 && gx < 4096) ? xb[gx] : 0.f;
    }
    U4 Bf2[3][2];
    {
        const uint4* wsrc = (const uint4*)w2b;
#pragma unroll
        for (int ct = 0; ct < 2; ++ct)
#pragma unroll
            for (int tp = 0; tp < 3; ++tp)
                Bf2[tp][ct].u = wsrc[(ct * 16 + m) * 12 + tp * 4 + quad];
    }
    float bv2[2];
#pragma unroll
    for (int ct = 0; ct < 2; ++ct) bv2[ct] = c2b[ct * 16 + m];
    float wv[80], bv1[16];
#pragma unroll
    for (int i = 0; i < 80; ++i) wv[i] = c1w[i];
#pragma unroll
    for (int i = 0; i < 16; ++i) bv1[i] = c1b[i];
    __syncthreads();

    for (int r = t; r < 536; r += 256) {
        int p = p0 + r;
        union { uint4 q[2]; __hip_bfloat16 hh[16]; } o;
        if (p >= 0 && p < 2048) {
            const float* s = xs + 2 * r;
            float s0 = s[0], s1 = s[1], s2 = s[2], s3 = s[3], s4 = s[4], s5 = s[5];
#pragma unroll
            for (int c = 0; c < 16; ++c) {
                const float* wr = wv + c * 5;
                float v0 = fmaf(wr[0], s0, fmaf(wr[1], s1, fmaf(wr[2], s2, fmaf(wr[3], s3, fmaf(wr[4], s4, bv1[c])))));
                float v1 = fmaf(wr[0], s1, fmaf(wr[1], s2, fmaf(wr[2], s3, fmaf(wr[3], s4, fmaf(wr[4], s5, bv1[c])))));
                o.hh[c] = __float2bfloat16(fmaxf(fmaxf(v0, v1), 0.f));
            }
        } else {
            o.q[0] = (uint4){0, 0, 0, 0};
            o.q[1] = (uint4){0, 0, 0, 0};
        }
        H1u[swz(2 * r)] = o.q[0];
        H1u[swz(2 * r + 1)] = o.q[1];
    }
    __syncthreads();

    __hip_bfloat16* H2h = (__hip_bfloat16*)H2u;
    for (int g = w; g < 33; g += 4) {
        f32x4 acc[2];
#pragma unroll
        for (int ct = 0; ct < 2; ++ct) acc[ct] = (f32x4){bv2[ct], bv2[ct], bv2[ct], bv2[ct]};
#pragma unroll
        for (int tp = 0; tp < 3; ++tp) {
            int u = 2 * (g * 16 + m + 2 * tp) + quad;
            U4 av; av.u = H1u[swz(u)];
            acc[0] = __builtin_amdgcn_mfma_f32_16x16x32_bf16(av.s8, Bf2[tp][0].s8, acc[0], 0, 0, 0);
            acc[1] = __builtin_amdgcn_mfma_f32_16x16x32_bf16(av.s8, Bf2[tp][1].s8, acc[1], 0, 0, 0);
        }
        int pp = g * 8 + quad * 2;
#pragma unroll
        for (int ct = 0; ct < 2; ++ct) {
            float o0 = fmaxf(fmaxf(acc[ct][0], acc[ct][1]), 0.f);
            float o1 = fmaxf(fmaxf(acc[ct][2], acc[ct][3]), 0.f);
            int ch = ct * 16 + m;
            int u0 = pp * 4 + (ch >> 3);
            H2h[swz(u0) * 8 + (ch & 7)] = __float2bfloat16(o0);
            H2h[swz(u0 + 4) * 8 + (ch & 7)] = __float2bfloat16(o1);
        }
    }
    __syncthreads();
    if (h == 0 && t < 8) H2u[swz((t >> 2) * 4 + (t & 3))] = (uint4){0, 0, 0, 0};
    if (h == 3 && t < 8) H2u[swz((258 + (t >> 2)) * 4 + (t & 3))] = (uint4){0, 0, 0, 0};
    __syncthreads();

    U4 Bf3[5][4];
    {
        const uint4* wsrc = (const uint4*)w3b;
#pragma unroll
        for (int ct = 0; ct < 4; ++ct)
#pragma unroll
            for (int kk = 0; kk < 5; ++kk)
                Bf3[kk][ct].u = wsrc[(ct * 16 + m) * 20 + kk * 4 + quad];
    }
    float bv3[4];
#pragma unroll
    for (int ct = 0; ct < 4; ++ct) bv3[ct] = c3b[ct * 16 + m];

#pragma unroll
    for (int ww = 0; ww < 2; ++ww) {
        int wl = w * 2 + ww;
        float sum[4] = {0.f, 0.f, 0.f, 0.f};
#pragma unroll
        for (int half = 0; half < 2; ++half) {
            int gp = wl * 2 + half;
            f32x4 acc[4];
#pragma unroll
            for (int ct = 0; ct < 4; ++ct) acc[ct] = (f32x4){bv3[ct], bv3[ct], bv3[ct], bv3[ct]};
#pragma unroll
            for (int kk = 0; kk < 5; ++kk) {
                int u = 4 * (gp * 16 + m + kk) + quad;
                U4 av; av.u = H2u[swz(u)];
#pragma unroll
                for (int ct = 0; ct < 4; ++ct)
                    acc[ct] = __builtin_amdgcn_mfma_f32_16x16x32_bf16(av.s8, Bf3[kk][ct].s8, acc[ct], 0, 0, 0);
            }
#pragma unroll
            for (int ct = 0; ct < 4; ++ct) {
                sum[ct] += fmaxf(acc[ct][0], 0.f) + fmaxf(acc[ct][1], 0.f)
                         + fmaxf(acc[ct][2], 0.f) + fmaxf(acc[ct][3], 0.f);
            }
        }
#pragma unroll
        for (int ct = 0; ct < 4; ++ct) {
            float s = sum[ct];
            s += __shfl_xor(s, 16, 64);
            s += __shfl_xor(s, 32, 64);
            sum[ct] = s;
        }
        float sv = (quad == 0) ? sum[0] : (quad == 1) ? sum[1] : (quad == 2) ? sum[2] : sum[3];
        int win = h * 8 + wl;
        h3b[b * 2048 + (quad * 16 + m) * 32 + win] = __float2bfloat16(sv * (1.f / 32.f));
    }
}

// ---------------- MFMA GEMM split-K=4: Cp[s][512][4096] partials, no bias
// 64x64 tile, BK=64, grid (64,8,4)=2048 blocks -> 8 blocks/CU, 32 waves/CU
__global__ __launch_bounds__(256) void lin_gemm_mfma(const __hip_bfloat16* __restrict__ A,
                                                     const float* __restrict__ Bw,
                                                     float* __restrict__ Cp) {
    __shared__ uint4 A_s[512];
    __shared__ uint4 B_s[512];
    int t = threadIdx.x;
    int col0 = blockIdx.x * 64;
    int row0 = blockIdx.y * 64;
    int ks = blockIdx.z;
    int w = t >> 6, lane = t & 63;
    int m = lane & 15, quad = lane >> 4;
    int lh = w >> 1, eh = w & 1;

    f32x4 acc[2][2];
#pragma unroll
    for (int li = 0; li < 2; ++li)
#pragma unroll
        for (int ei = 0; ei < 2; ++ei) acc[li][ei] = (f32x4){0.f, 0.f, 0.f, 0.f};

    for (int ki = 0; ki < 8; ++ki) {
        int k0 = ks * 512 + ki * 64;
#pragma unroll
        for (int p = 0; p < 2; ++p) {
            int id = p * 256 + t;
            int r = id >> 3, u = id & 7;
            A_s[r * 8 + (u ^ (r & 7))] = *(const uint4*)(A + (row0 + r) * 2048 + k0 + u * 8);
            const float4* s4 = (const float4*)(Bw + (size_t)(col0 + r) * 2048 + k0 + u * 8);
            float4 f0 = s4[0], f1 = s4[1];
            union { uint4 q; __hip_bfloat16 hh[8]; } o;
            o.hh[0] = __float2bfloat16(f0.x); o.hh[1] = __float2bfloat16(f0.y);
            o.hh[2] = __float2bfloat16(f0.z); o.hh[3] = __float2bfloat16(f0.w);
            o.hh[4] = __float2bfloat16(f1.x); o.hh[5] = __float2bfloat16(f1.y);
            o.hh[6] = __float2bfloat16(f1.z); o.hh[7] = __float2bfloat16(f1.w);
            B_s[r * 8 + (u ^ (r & 7))] = o.q;
        }
        __syncthreads();
#pragma unroll
        for (int c = 0; c < 2; ++c) {
            int uu = c * 4 + quad;
            U4 av[2], bv[2];
#pragma unroll
            for (int li = 0; li < 2; ++li) {
                int ra = (lh * 2 + li) * 16 + m;
                av[li].u = A_s[ra * 8 + (uu ^ (ra & 7))];
            }
#pragma unroll
            for (int ei = 0; ei < 2; ++ei) {
                int rb = (eh * 2 + ei) * 16 + m;
                bv[ei].u = B_s[rb * 8 + (uu ^ (rb & 7))];
            }
#pragma unroll
            for (int li = 0; li < 2; ++li)
#pragma unroll
                for (int ei = 0; ei < 2; ++ei)
                    acc[li][ei] = __builtin_amdgcn_mfma_f32_16x16x32_bf16(av[li].s8, bv[ei].s8, acc[li][ei], 0, 0, 0);
        }
        __syncthreads();
    }
    float* Cb = Cp + (size_t)ks * 2097152;
#pragma unroll
    for (int li = 0; li < 2; ++li)
#pragma unroll
        for (int ei = 0; ei < 2; ++ei) {
            int col = col0 + (eh * 2 + ei) * 16 + m;
#pragma unroll
            for (int reg = 0; reg < 4; ++reg) {
                int row = row0 + (lh * 2 + li) * 16 + quad * 4 + reg;
                Cb[row * 4096 + col] = acc[li][ei][reg];
            }
        }
}

// ---------------- fused double {layernorm + mamba}, MFMA in/out-proj
struct MambaP {
    const float *lng, *lnb, *cvw, *cvb, *xpw, *dtw, *dtb, *al, *dp;
};

__global__ __launch_bounds__(256) void mamba2_kernel(const float* __restrict__ part,
                                                     const float* __restrict__ lb,
                                                     const __hip_bfloat16* __restrict__ winb,
                                                     const __hip_bfloat16* __restrict__ owb,
                                                     MambaP p1, MambaP p2,
                                                     float* __restrict__ out) {
    __shared__ float X[64][68];
    __shared__ float XI[64][68];
    __shared__ float DTS[64][68];
    __shared__ float W12[64][14];
    __shared__ uint4 XBu[512];
    int b = blockIdx.x, t = threadIdx.x;
    int lane = t & 63, w = t >> 6, m = lane & 15, quad = lane >> 4;
    int l0 = w * 16;

    {
        const float4* s0 = (const float4*)(part + (size_t)b * 4096);
        const float4* s1 = (const float4*)(part + 2097152 + (size_t)b * 4096);
        const float4* s2 = (const float4*)(part + 2 * 2097152 + (size_t)b * 4096);
        const float4* s3 = (const float4*)(part + 3 * 2097152 + (size_t)b * 4096);
        const float4* bb = (const float4*)lb;
        for (int i = t; i < 1024; i += 256) {
            float4 a = s0[i], c = s1[i], d = s2[i], e = s3[i], f = bb[i];
            float4 v;
            v.x = ((a.x + c.x) + (d.x + e.x)) + f.x;
            v.y = ((a.y + c.y) + (d.y + e.y)) + f.y;
            v.z = ((a.z + c.z) + (d.z + e.z)) + f.z;
            v.w = ((a.w + c.w) + (d.w + e.w)) + f.w;
            *(float4*)(&X[i >> 4][(i & 15) * 4]) = v;
        }
    }
    __syncthreads();

    for (int blk = 0; blk < 2; ++blk) {
        MambaP P = blk ? p2 : p1;

        {
            int l = t >> 2, q = t & 3;
            float4 xv[4];
            const float4* xr = (const float4*)(&X[l][q * 16]);
#pragma unroll
            for (int j = 0; j < 4; ++j) xv[j] = xr[j];
            float s = 0.f;
#pragma unroll
            for (int j = 0; j < 4; ++j) s += (xv[j].x + xv[j].y) + (xv[j].z + xv[j].w);
            s += __shfl_xor(s, 1, 4);
            s += __shfl_xor(s, 2, 4);
            float mm = s * (1.f / 64.f);
            float v = 0.f;
#pragma unroll
            for (int j = 0; j < 4; ++j) {
                float dx;
                dx = xv[j].x - mm; v = fmaf(dx, dx, v);
                dx = xv[j].y - mm; v = fmaf(dx, dx, v);
                dx = xv[j].z - mm; v = fmaf(dx, dx, v);
                dx = xv[j].w - mm; v = fmaf(dx, dx, v);
            }
            v += __shfl_xor(v, 1, 4);
            v += __shfl_xor(v, 2, 4);
            float rstd = rsqrtf(v * (1.f / 64.f) + 1e-5f);
            const float4* g4 = (const float4*)(P.lng + q * 16);
            const float4* bb4 = (const float4*)(P.lnb + q * 16);
            union { uint4 qq[2]; __hip_bfloat16 hh[16]; } o;
#pragma unroll
            for (int j = 0; j < 4; ++j) {
                float4 g = g4[j], bb = bb4[j];
                o.hh[j * 4 + 0] = __float2bfloat16((xv[j].x - mm) * rstd * g.x + bb.x);
                o.hh[j * 4 + 1] = __float2bfloat16((xv[j].y - mm) * rstd * g.y + bb.y);
                o.hh[j * 4 + 2] = __float2bfloat16((xv[j].z - mm) * rstd * g.z + bb.z);
                o.hh[j * 4 + 3] = __float2bfloat16((xv[j].w - mm) * rstd * g.w + bb.w);
            }
            XBu[idx8(l, q * 2)] = o.qq[0];
            XBu[idx8(l, q * 2 + 1)] = o.qq[1];
        }
        __syncthreads();

        {
            const uint4* wp = (const uint4*)winb + blk * 1024;
            U4 Bf[8][2];
#pragma unroll
            for (int nt = 0; nt < 8; ++nt)
#pragma unroll
                for (int c = 0; c < 2; ++c)
                    Bf[nt][c].u = wp[(nt * 16 + m) * 8 + c * 4 + quad];
            f32x4 acc[8];
#pragma unroll
            for (int nt = 0; nt < 8; ++nt) acc[nt] = (f32x4){0.f, 0.f, 0.f, 0.f};
#pragma unroll
            for (int c = 0; c < 2; ++c) {
                U4 av; av.u = XBu[idx8(l0 + m, c * 4 + quad)];
#pragma unroll
                for (int nt = 0; nt < 8; ++nt)
                    acc[nt] = __builtin_amdgcn_mfma_f32_16x16x32_bf16(av.s8, Bf[nt][c].s8, acc[nt], 0, 0, 0);
            }
#pragma unroll
            for (int nt = 0; nt < 4; ++nt)
#pragma unroll
                for (int reg = 0; reg < 4; ++reg)
                    XI[l0 + quad * 4 + reg][nt * 16 + m] = acc[nt][reg];
#pragma unroll
            for (int nt = 4; nt < 8; ++nt)
#pragma unroll
                for (int reg = 0; reg < 4; ++reg)
                    X[l0 + quad * 4 + reg][(nt - 4) * 16 + m] = acc[nt][reg];
        }
        __syncthreads();

        {
            int d = t & 63, lg = t >> 6;
            int lc = lg * 16;
            float cur[16];
            float prev = (lc == 0) ? 0.f : XI[lc - 1][d];
#pragma unroll
            for (int j = 0; j < 16; ++j) cur[j] = XI[lc + j][d];
            __syncthreads();
            float w0 = P.cvw[d * 2], w1 = P.cvw[d * 2 + 1], cb = P.cvb[d];
#pragma unroll
            for (int j = 0; j < 16; ++j) {
                float xp = (j == 0) ? prev : cur[j - 1];
                float v = fmaf(w0, xp, fmaf(w1, cur[j], cb));
                XI[lc + j][d] = v / (1.f + __expf(-v));
            }
        }
        __syncthreads();

        {
            int l = t & 63, jg = t >> 6;
            float4 xrow[16];
            const float4* xr = (const float4*)(&XI[l][0]);
#pragma unroll
            for (int k4 = 0; k4 < 16; ++k4) xrow[k4] = xr[k4];
#pragma unroll
            for (int jj = 0; jj < 3; ++jj) {
                int j = jg * 3 + jj;
                const float4* wr = (const float4*)(P.xpw + j * 64);
                float a0 = 0.f, a1 = 0.f, a2 = 0.f, a3 = 0.f;
#pragma unroll
                for (int k4 = 0; k4 < 16; ++k4) {
                    float4 wvv = wr[k4];
                    a0 = fmaf(xrow[k4].x, wvv.x, a0);
                    a1 = fmaf(xrow[k4].y, wvv.y, a1);
                    a2 = fmaf(xrow[k4].z, wvv.z, a2);
                    a3 = fmaf(xrow[k4].w, wvv.w, a3);
                }
                float accv = (a0 + a1) + (a2 + a3);
                int slot = (j < 4) ? j : ((j < 8) ? (4 + (j - 4) * 2) : (5 + (j - 8) * 2));
                W12[l][slot] = accv;
            }
        }
        __syncthreads();

        {
            int l = t & 63, dg = t >> 6;
            float d0 = W12[l][0], d1 = W12[l][1], d2 = W12[l][2], d3 = W12[l][3];
#pragma unroll 4
            for (int jj = 0; jj < 16; ++jj) {
                int d = dg * 16 + jj;
                const float4 wvv = *(const float4*)(P.dtw + d * 4);
                float xdt = fmaf(wvv.x, d0, fmaf(wvv.y, d1, fmaf(wvv.z, d2, fmaf(wvv.w, d3, P.dtb[d]))));
                DTS[d][l] = fmaxf(xdt, 0.f) + __logf(1.f + __expf(-fabsf(xdt)));
            }
        }
        __syncthreads();

        {
            int d = t >> 2, n = t & 3;
            float Aval = -__expf(P.al[d * 4 + n]);
            float dpv = P.dp[d];
            const float* dtrow = &DTS[d][0];
            ushort* YBh = (ushort*)XBu;
            float h = 0.f;
#pragma unroll 4
            for (int l = 0; l < 64; ++l) {
                float dtv = dtrow[l];
                float dA = __expf(dtv * Aval);
                float uv = XI[l][d];
                float2 bc = *(const float2*)(&W12[l][4 + n * 2]);
                h = fmaf(dA, h, dtv * bc.x * uv);
                float part2 = h * bc.y;
                part2 += __shfl_xor(part2, 1, 4);
                part2 += __shfl_xor(part2, 2, 4);
                if (n == 0) {
                    float zv = X[l][d];
                    float yv = part2 + dpv * uv;
                    float gy = yv * (zv / (1.f + __expf(-zv)));
                    BF cv; cv.h = __float2bfloat16(gy);
                    YBh[idx8(l, d >> 3) * 8 + (d & 7)] = cv.us;
                }
            }
        }
        __syncthreads();

        {
            const uint4* wp = (const uint4*)owb + blk * 512;
            U4 Bf[4][2];
#pragma unroll
            for (int nt = 0; nt < 4; ++nt)
#pragma unroll
                for (int c = 0; c < 2; ++c)
                    Bf[nt][c].u = wp[(nt * 16 + m) * 8 + c * 4 + quad];
            f32x4 acc[4];
#pragma unroll
            for (int nt = 0; nt < 4; ++nt) acc[nt] = (f32x4){0.f, 0.f, 0.f, 0.f};
#pragma unroll
            for (int c = 0; c < 2; ++c) {
                U4 av; av.u = XBu[idx8(l0 + m, c * 4 + quad)];
#pragma unroll
                for (int nt = 0; nt < 4; ++nt)
                    acc[nt] = __builtin_amdgcn_mfma_f32_16x16x32_bf16(av.s8, Bf[nt][c].s8, acc[nt], 0, 0, 0);
            }
            if (blk == 0) {
#pragma unroll
                for (int nt = 0; nt < 4; ++nt)
#pragma unroll
                    for (int reg = 0; reg < 4; ++reg)
                        X[l0 + quad * 4 + reg][nt * 16 + m] = acc[nt][reg];
            } else {
                float* ob = out + b * 4096;
#pragma unroll
                for (int nt = 0; nt < 4; ++nt)
#pragma unroll
                    for (int reg = 0; reg < 4; ++reg)
                        ob[(l0 + quad * 4 + reg) * 64 + nt * 16 + m] = acc[nt][reg];
            }
        }
        __syncthreads();
    }
}

extern "C" void kernel_launch(void* const* d_in, const int* in_sizes, int n_in,
                              void* d_out, int out_size, void* d_ws, size_t ws_size,
                              hipStream_t stream) {
    const float* x   = (const float*)d_in[0];
    const float* c1w = (const float*)d_in[1];
    const float* c1b = (const float*)d_in[2];
    const float* c2w = (const float*)d_in[3];
    const float* c2b = (const float*)d_in[4];
    const float* c3w = (const float*)d_in[5];
    const float* c3b = (const float*)d_in[6];
    const float* lw  = (const float*)d_in[7];
    const float* lb  = (const float*)d_in[8];

    MambaP p1, p2;
    p1.lng = (const float*)d_in[9];  p1.lnb = (const float*)d_in[10];
    p1.cvw = (const float*)d_in[12]; p1.cvb = (const float*)d_in[13];
    p1.xpw = (const float*)d_in[14]; p1.dtw = (const float*)d_in[15];
    p1.dtb = (const float*)d_in[16]; p1.al  = (const float*)d_in[17];
    p1.dp  = (const float*)d_in[18];
    p2.lng = (const float*)d_in[20]; p2.lnb = (const float*)d_in[21];
    p2.cvw = (const float*)d_in[23]; p2.cvb = (const float*)d_in[24];
    p2.xpw = (const float*)d_in[25]; p2.dtw = (const float*)d_in[26];
    p2.dtb = (const float*)d_in[27]; p2.al  = (const float*)d_in[28];
    p2.dp  = (const float*)d_in[29];
    const float* in1w = (const float*)d_in[11];
    const float* in2w = (const float*)d_in[22];
    const float* ow1  = (const float*)d_in[19];
    const float* ow2  = (const float*)d_in[30];

    const size_t MB = 1024 * 1024;
    char* base = (char*)d_ws;
    __hip_bfloat16* h3b  = (__hip_bfloat16*)base;                           // 2 MB
    float* part          = (float*)(base + 4 * MB);                         // 32 MB (4 x 8 MB partials)
    __hip_bfloat16* w2b  = (__hip_bfloat16*)(base + 40 * MB);               // 6 KB
    __hip_bfloat16* w3b  = (__hip_bfloat16*)(base + 40 * MB + 64 * 1024);   // 20 KB
    __hip_bfloat16* winb = (__hip_bfloat16*)(base + 40 * MB + 256 * 1024);  // 32 KB
    __hip_bfloat16* owb  = (__hip_bfloat16*)(base + 40 * MB + 512 * 1024);  // 16 KB
    float* outp = (float*)d_out;

    prep_w<<<dim3(148), dim3(256), 0, stream>>>(c2w, w2b, c3w, w3b,
                                                in1w, in2w, winb, ow1, ow2, owb);
    conv_trunk<<<dim3(4, NB), dim3(256), 0, stream>>>(x, c1w, c1b, w2b, c2b, w3b, c3b, h3b);
    lin_gemm_mfma<<<dim3(64, 8, 4), dim3(256), 0, stream>>>(h3b, lw, part);
    mamba2_kernel<<<dim3(NB), dim3(256), 0, stream>>>(part, lb, winb, owb, p1, p2, outp);
}